// Round 5
// baseline (795.427 us; speedup 1.0000x reference)
//
#include <hip/hip_runtime.h>
#include <hip/hip_bf16.h>
#include <hip/hip_fp16.h>

#define N_NODES 50000
#define N_EDGES 400000
#define D 16
#define HID 64

typedef unsigned short ushort_t;

// ---------------- workspace layout (atomic-accumulation path) ----------------
// [DEG_OFF]  [N] int degree
// [ACC_OFF]  [N*D] f32 accumulator (messages summed here directly)
// [PREP_OFF] f32 weight table: 64 j-rows x 64 dwords (256B-aligned rows)
//            [0..31] W1[j][k]  [32..47] W2[i][j] (i=0..15)  [48] b1[j]  pad
//            then 16 dwords of b2
#define DEG_OFF   0
#define ACC_OFF   (N_NODES)
#define PREP_OFF  (N_NODES + N_NODES * D)          // 850000 ints, 16B-aligned
#define PREP_DW   (64 * 64 + 16)
#define WS_NEEDED_BYTES ((size_t)(PREP_OFF + PREP_DW) * 4 + 64)
#define ZERO_BYTES ((size_t)(N_NODES + N_NODES * D) * 4)

// ---------------------------------------------------------------------------
// dtype helpers
// ---------------------------------------------------------------------------
__device__ __forceinline__ float bf_bits(ushort_t us) {
    return __uint_as_float(((unsigned)us) << 16);
}
__device__ __forceinline__ float lo_bf(unsigned u) { return __uint_as_float(u << 16); }
__device__ __forceinline__ float hi_bf(unsigned u) { return __uint_as_float(u & 0xffff0000u); }
__device__ __forceinline__ ushort_t f2bf(float v) {
    unsigned u = __float_as_uint(v);
    unsigned r = (u + 0x7fffu + ((u >> 16) & 1u)) >> 16;
    return (ushort_t)r;
}
__device__ __forceinline__ float ld_f(const void* p, int idx, int f32) {
    return f32 ? ((const float*)p)[idx]
               : bf_bits(((const ushort_t*)p)[idx]);
}

__device__ __forceinline__ void load16(const void* __restrict__ p, long long base,
                                       int f32, float* o) {
    if (f32) {
        const float4* q = (const float4*)((const float*)p + base);
        float4 a = q[0], b = q[1], c = q[2], d = q[3];
        o[0]=a.x; o[1]=a.y; o[2]=a.z; o[3]=a.w;
        o[4]=b.x; o[5]=b.y; o[6]=b.z; o[7]=b.w;
        o[8]=c.x; o[9]=c.y; o[10]=c.z; o[11]=c.w;
        o[12]=d.x; o[13]=d.y; o[14]=d.z; o[15]=d.w;
    } else {
        const uint4* q = (const uint4*)((const ushort_t*)p + base);
        uint4 a = q[0], b = q[1];
        unsigned u[8] = {a.x, a.y, a.z, a.w, b.x, b.y, b.z, b.w};
#pragma unroll
        for (int k = 0; k < 8; k++) {
            o[2 * k]     = lo_bf(u[k]);
            o[2 * k + 1] = hi_bf(u[k]);
        }
    }
}

__device__ __forceinline__ void load_edge(const void* __restrict__ ei, int e, int is64,
                                          int& s, int& d) {
    if (is64) {
        const long long* p = (const long long*)ei;
        s = (int)p[e];
        d = (int)p[N_EDGES + e];
    } else {
        const int* p = (const int*)ei;
        s = p[e];
        d = p[N_EDGES + e];
    }
}

// Parallel flag detection (wave 0, ballot): f32-vs-bf16 from first 256 x halves,
// i64-vs-i32 from first 16 edge values. Per-block, no cross-block dependency.
__device__ __forceinline__ void detect_flags_par(const void* x, const void* ei,
                                                 int* flags) {
    int t = threadIdx.x;
    if (t < 64) {
        const ushort_t* h = (const ushort_t*)x;
        int bad = 0;
#pragma unroll
        for (int k = 0; k < 4; k++) {
            float v = bf_bits(h[4 * t + k]);
            if (!(v == v) || fabsf(v) > 1.0e6f) bad = 1;
        }
        unsigned long long mb = __ballot(bad);
        const long long* p = (const long long*)ei;
        int bad64 = 0;
        if (t < 16) {
            long long v = p[t];
            bad64 = (v < 0 || v >= N_NODES) ? 1 : 0;
        }
        unsigned long long m64 = __ballot(bad64);
        if (t == 0) {
            flags[0] = mb ? 1 : 0;
            flags[1] = m64 ? 0 : 1;
        }
    }
}

// ---------------------------------------------------------------------------
// Full-MLP per-edge math, f32 (safety path for f32 inputs)
// ---------------------------------------------------------------------------
__device__ __forceinline__ void edge_math_v4(
    const float* __restrict__ sW1, const float* __restrict__ sW2t,
    const float* __restrict__ sb1, const float* __restrict__ sb2,
    const float* xs, const float* xd, float coef,
    float* ms, float* md)
{
    float vs[D], vd[D];
#pragma unroll
    for (int i = 0; i < D; i++) { vs[i] = sb2[i]; vd[i] = sb2[i]; }
#pragma unroll 4
    for (int j = 0; j < HID; j++) {
        float hs = sb1[j], hd = sb1[j];
        const float4* w4 = (const float4*)&sW1[j * 2 * D];
#pragma unroll
        for (int t = 0; t < 4; t++) {
            float4 wv = w4[t];
            int k = 4 * t;
            hs = fmaf(wv.x, xs[k],     hs); hd = fmaf(wv.x, xd[k],     hd);
            hs = fmaf(wv.y, xs[k + 1], hs); hd = fmaf(wv.y, xd[k + 1], hd);
            hs = fmaf(wv.z, xs[k + 2], hs); hd = fmaf(wv.z, xd[k + 2], hd);
            hs = fmaf(wv.w, xs[k + 3], hs); hd = fmaf(wv.w, xd[k + 3], hd);
        }
#pragma unroll
        for (int t = 0; t < 4; t++) {
            float4 wv = w4[4 + t];
            int k = 4 * t;
            hs = fmaf(wv.x, xd[k],     hs); hd = fmaf(wv.x, xs[k],     hd);
            hs = fmaf(wv.y, xd[k + 1], hs); hd = fmaf(wv.y, xs[k + 1], hd);
            hs = fmaf(wv.z, xd[k + 2], hs); hd = fmaf(wv.z, xs[k + 2], hd);
            hs = fmaf(wv.w, xd[k + 3], hs); hd = fmaf(wv.w, xs[k + 3], hd);
        }
        hs = fmaxf(hs, 0.0f);
        hd = fmaxf(hd, 0.0f);
        const float4* w24 = (const float4*)&sW2t[j * D];
#pragma unroll
        for (int t = 0; t < 4; t++) {
            float4 u = w24[t];
            int i = 4 * t;
            vs[i]     = fmaf(u.x, hs, vs[i]);     vd[i]     = fmaf(u.x, hd, vd[i]);
            vs[i + 1] = fmaf(u.y, hs, vs[i + 1]); vd[i + 1] = fmaf(u.y, hd, vd[i + 1]);
            vs[i + 2] = fmaf(u.z, hs, vs[i + 2]); vd[i + 2] = fmaf(u.z, hd, vd[i + 2]);
            vs[i + 3] = fmaf(u.w, hs, vs[i + 3]); vd[i + 3] = fmaf(u.w, hd, vd[i + 3]);
        }
    }
    float ns = 0.0f, nd = 0.0f;
#pragma unroll
    for (int i = 0; i < D; i++) { ns = fmaf(vs[i], vs[i], ns); nd = fmaf(vd[i], vd[i], nd); }
    float is_ = 1.0f / fmaxf(sqrtf(ns), 1e-12f);
    float id_ = 1.0f / fmaxf(sqrtf(nd), 1e-12f);
#pragma unroll
    for (int i = 0; i < D; i++) { vs[i] *= is_; vd[i] *= id_; }
    float dot1 = 0.0f;
#pragma unroll
    for (int i = 0; i < D; i++) dot1 = fmaf(vd[i], xd[i], dot1);
#pragma unroll
    for (int i = 0; i < D; i++) ms[i] = fmaf(-2.0f * dot1, vd[i], xd[i]);
    float dot2 = 0.0f;
#pragma unroll
    for (int i = 0; i < D; i++) dot2 = fmaf(vs[i], ms[i], dot2);
#pragma unroll
    for (int i = 0; i < D; i++) ms[i] = coef * fmaf(-2.0f * dot2, vs[i], ms[i]);
    float dot3 = 0.0f;
#pragma unroll
    for (int i = 0; i < D; i++) dot3 = fmaf(vs[i], xs[i], dot3);
#pragma unroll
    for (int i = 0; i < D; i++) md[i] = fmaf(-2.0f * dot3, vs[i], xs[i]);
    float dot4 = 0.0f;
#pragma unroll
    for (int i = 0; i < D; i++) dot4 = fmaf(vd[i], md[i], dot4);
#pragma unroll
    for (int i = 0; i < D; i++) md[i] = coef * fmaf(-2.0f * dot4, vd[i], md[i]);
}

// ===========================================================================
// 1) Degree count (int atomics) + block 0 packs the f32 weight table.
// ===========================================================================
__global__ __launch_bounds__(256) void atm_deg_kernel(
    const void* __restrict__ ei,
    const void* __restrict__ x,
    const void* __restrict__ W1,
    const void* __restrict__ b1,
    const void* __restrict__ W2,
    const void* __restrict__ b2,
    int* __restrict__ wsI)
{
    __shared__ int sfl[2];
    detect_flags_par(x, ei, sfl);
    __syncthreads();
    int i64 = sfl[1];

    if (blockIdx.x == 0) {
        // pack f32 weight table (bf16 interpretation; unused by the f32 path)
        float* pf = (float*)(wsI + PREP_OFF);
        const ushort_t* W1b = (const ushort_t*)W1;
        const ushort_t* W2b = (const ushort_t*)W2;
        const ushort_t* b1b = (const ushort_t*)b1;
        const ushort_t* b2b = (const ushort_t*)b2;
        for (int idx = threadIdx.x; idx < 64 * 64; idx += 256) {
            int j = idx >> 6, w = idx & 63;
            float val = 0.0f;
            if (w < 32)      val = bf_bits(W1b[j * 32 + w]);
            else if (w < 48) val = bf_bits(W2b[(w - 32) * HID + j]);
            else if (w == 48) val = bf_bits(b1b[j]);
            pf[idx] = val;
        }
        if (threadIdx.x < D)
            pf[64 * 64 + threadIdx.x] = bf_bits(b2b[threadIdx.x]);
    }

    int e = blockIdx.x * 256 + threadIdx.x;
    if (e >= N_EDGES) return;
    int s, d;
    load_edge(ei, e, i64, s, d);
    atomicAdd(&wsI[DEG_OFF + s], 1);
    atomicAdd(&wsI[DEG_OFF + d], 1);
}

// ===========================================================================
// 2) Edge kernel: R3-proven math (1 lane/edge, SGPR weights, f32 FMA), then
//    messages accumulate DIRECTLY via f32 atomics into acc (3.2 MB, L2-hot).
//    Kills the CSR count/scan/gather pipeline and 100 MB of msg traffic.
// ===========================================================================
__global__ __launch_bounds__(256) void atm_edge_kernel(
    const void* __restrict__ x,
    const void* __restrict__ ei,
    const void* __restrict__ W1,
    const void* __restrict__ b1,
    const void* __restrict__ W2,
    const void* __restrict__ b2,
    const float* __restrict__ prep,
    int* __restrict__ wsI)
{
    __shared__ __align__(16) float sW1f[HID * 2 * D];   // f32 path only
    __shared__ __align__(16) float sW2tf[HID * D];      // f32 path only
    __shared__ float sb1[HID];
    __shared__ float sb2[D];
    __shared__ int sfl[2];

    detect_flags_par(x, ei, sfl);
    __syncthreads();
    int f32 = sfl[0], i64 = sfl[1];
    int t = threadIdx.x;

    if (f32) {
        for (int idx = t; idx < HID * 2 * D; idx += 256)
            sW1f[idx] = ld_f(W1, idx, 1);
        for (int idx = t; idx < HID * D; idx += 256) {
            int j = idx / D, i = idx % D;
            sW2tf[idx] = ld_f(W2, i * HID + j, 1);
        }
        if (t < HID) sb1[t] = ld_f(b1, t, 1);
        if (t < D)  sb2[t] = ld_f(b2, t, 1);
        __syncthreads();
    }

    int e = blockIdx.x * 256 + t;
    if (e >= N_EDGES) return;

    int s, d;
    load_edge(ei, e, i64, s, d);
    float degs = (float)wsI[DEG_OFF + s];
    float degd = (float)wsI[DEG_OFF + d];
    float coef = (1.0f / sqrtf(fmaxf(degs, 1e-5f))) * (1.0f / sqrtf(fmaxf(degd, 1e-5f)));
    float* acc = (float*)(wsI + ACC_OFF);

    float xs[D], xd[D];
    load16(x, (long long)s * D, f32, xs);
    load16(x, (long long)d * D, f32, xd);

    float ms[D], md[D];
    if (!f32) {
        const float* b2f = prep + 64 * 64;
        float vs[D], vd[D];
#pragma unroll
        for (int i = 0; i < D; i++) { vs[i] = b2f[i]; vd[i] = b2f[i]; }

#pragma unroll 1
        for (int j = 0; j < HID; j++) {
            const float* w = prep + (j << 6);    // uniform -> s_load
            float b1j = w[48];
            float hs0 = b1j, hs1 = 0.0f, hd0 = b1j, hd1 = 0.0f;
#pragma unroll
            for (int k = 0; k < 8; k++) {        // [xs | .] part
                hs0 = fmaf(w[k],     xs[k],     hs0);
                hd0 = fmaf(w[k],     xd[k],     hd0);
                hs1 = fmaf(w[8 + k], xs[8 + k], hs1);
                hd1 = fmaf(w[8 + k], xd[8 + k], hd1);
            }
#pragma unroll
            for (int k = 0; k < 8; k++) {        // [. | xd] part
                hs0 = fmaf(w[16 + k], xd[k],     hs0);
                hd0 = fmaf(w[16 + k], xs[k],     hd0);
                hs1 = fmaf(w[24 + k], xd[8 + k], hs1);
                hd1 = fmaf(w[24 + k], xs[8 + k], hd1);
            }
            float hs = fmaxf(hs0 + hs1, 0.0f);
            float hd = fmaxf(hd0 + hd1, 0.0f);
#pragma unroll
            for (int i = 0; i < D; i++) {
                vs[i] = fmaf(w[32 + i], hs, vs[i]);
                vd[i] = fmaf(w[32 + i], hd, vd[i]);
            }
        }

        float ns = 0.0f, nd = 0.0f;
#pragma unroll
        for (int i = 0; i < D; i++) { ns = fmaf(vs[i], vs[i], ns); nd = fmaf(vd[i], vd[i], nd); }
        float is_ = 1.0f / fmaxf(sqrtf(ns), 1e-12f);
        float id_ = 1.0f / fmaxf(sqrtf(nd), 1e-12f);
#pragma unroll
        for (int i = 0; i < D; i++) { vs[i] *= is_; vd[i] *= id_; }

        float dot1 = 0.0f;
#pragma unroll
        for (int i = 0; i < D; i++) dot1 = fmaf(vd[i], xd[i], dot1);
#pragma unroll
        for (int i = 0; i < D; i++) ms[i] = fmaf(-2.0f * dot1, vd[i], xd[i]);
        float dot2 = 0.0f;
#pragma unroll
        for (int i = 0; i < D; i++) dot2 = fmaf(vs[i], ms[i], dot2);
#pragma unroll
        for (int i = 0; i < D; i++) ms[i] = coef * fmaf(-2.0f * dot2, vs[i], ms[i]);
        float dot3 = 0.0f;
#pragma unroll
        for (int i = 0; i < D; i++) dot3 = fmaf(vs[i], xs[i], dot3);
#pragma unroll
        for (int i = 0; i < D; i++) md[i] = fmaf(-2.0f * dot3, vs[i], xs[i]);
        float dot4 = 0.0f;
#pragma unroll
        for (int i = 0; i < D; i++) dot4 = fmaf(vd[i], md[i], dot4);
#pragma unroll
        for (int i = 0; i < D; i++) md[i] = coef * fmaf(-2.0f * dot4, vd[i], md[i]);
    } else {
        edge_math_v4(sW1f, sW2tf, sb1, sb2, xs, xd, coef, ms, md);
    }

#pragma unroll
    for (int i = 0; i < D; i++) atomicAdd(&acc[s * D + i], ms[i]);
#pragma unroll
    for (int i = 0; i < D; i++) atomicAdd(&acc[d * D + i], md[i]);
}

// ===========================================================================
// 3) Finalize: out = bf16(relu(x + acc)), 4 elements per thread.
// ===========================================================================
__global__ __launch_bounds__(256) void atm_fin_kernel(
    const void* __restrict__ x,
    const void* __restrict__ ei,
    const int* __restrict__ wsI,
    void* __restrict__ out)
{
    __shared__ int sfl[2];
    detect_flags_par(x, ei, sfl);
    __syncthreads();
    int f32 = sfl[0];

    int q = blockIdx.x * 256 + threadIdx.x;       // quad index
    if (q >= (N_NODES * D) / 4) return;
    long long base = (long long)q * 4;

    const float* acc = (const float*)(wsI + ACC_OFF);
    float4 a = *(const float4*)(acc + base);

    float4 xv;
    if (f32) {
        xv = *(const float4*)((const float*)x + base);
    } else {
        uint2 u = *(const uint2*)((const ushort_t*)x + base);
        xv.x = lo_bf(u.x); xv.y = hi_bf(u.x);
        xv.z = lo_bf(u.y); xv.w = hi_bf(u.y);
    }
    float4 r;
    r.x = fmaxf(xv.x + a.x, 0.0f);
    r.y = fmaxf(xv.y + a.y, 0.0f);
    r.z = fmaxf(xv.z + a.z, 0.0f);
    r.w = fmaxf(xv.w + a.w, 0.0f);
    if (f32) {
        *(float4*)((float*)out + base) = r;
    } else {
        uint2 o;
        o.x = (unsigned)f2bf(r.x) | ((unsigned)f2bf(r.y) << 16);
        o.y = (unsigned)f2bf(r.z) | ((unsigned)f2bf(r.w) << 16);
        *(uint2*)((ushort_t*)out + base) = o;
    }
}

// ===========================================================================
extern "C" void kernel_launch(void* const* d_in, const int* in_sizes, int n_in,
                              void* d_out, int out_size, void* d_ws, size_t ws_size,
                              hipStream_t stream)
{
    const void* x  = d_in[0];
    const void* ei = d_in[1];
    const void* W1 = d_in[2];
    const void* b1 = d_in[3];
    const void* W2 = d_in[4];
    const void* b2 = d_in[5];

    int blk = 256;
    int* wsI = (int*)d_ws;
    hipMemsetAsync(d_ws, 0, ZERO_BYTES, stream);
    atm_deg_kernel<<<(N_EDGES + blk - 1) / blk, blk, 0, stream>>>(
        ei, x, W1, b1, W2, b2, wsI);
    atm_edge_kernel<<<(N_EDGES + blk - 1) / blk, blk, 0, stream>>>(
        x, ei, W1, b1, W2, b2, (const float*)(wsI + PREP_OFF), wsI);
    atm_fin_kernel<<<((N_NODES * D / 4) + blk - 1) / blk, blk, 0, stream>>>(
        x, ei, wsI, d_out);
}

// Round 6
// 210.026 us; speedup vs baseline: 3.7873x; 3.7873x over previous
//
#include <hip/hip_runtime.h>
#include <hip/hip_bf16.h>
#include <hip/hip_fp16.h>
#include <hip/hip_cooperative_groups.h>

namespace cg = cooperative_groups;

#define N_NODES 50000
#define N_EDGES 400000
#define D 16
#define HID 64

#define SCAN_B 256
#define SCAN_G ((N_NODES + SCAN_B - 1) / SCAN_B)   // 196

typedef unsigned short ushort_t;

// ---------------- int-indexed workspace layout (CSR path) ----------------
#define CNT4_OFF  0                       // [4][N] replicated counts
#define DEG_OFF   (4 * N_NODES)           // [N] total degree
#define OFF_OFF   (5 * N_NODES)           // [N+1] CSR offsets
#define CUR_OFF   (6 * N_NODES + 1)       // [N] claim cursors
#define BS_OFF    (7 * N_NODES + 1)       // [SCAN_G] block sums
// 64B-aligned msg base: 64B f32 msg rows must not straddle cache lines
// (R3 had 16B alignment -> ~50% of rows straddled -> +23MB HBM write amp).
#define MSG_OFF_I (((BS_OFF + SCAN_G) + 15) & ~15) // [2E*16] fp32 msgs
// f32 weight table: 64 j-rows x 64 dwords (256B-aligned rows)
//   [0..31] W1[j][k]  [32..47] W2[i][j] (i=0..15)  [48] b1[j]  pad
//   then 16 dwords of b2
#define PREP_OFF  (MSG_OFF_I + 2 * N_EDGES * D)
#define PREP_DW   (64 * 64 + 16)
#define CSR_NEEDED_BYTES ((size_t)(PREP_OFF + PREP_DW) * 4 + 64)

// ---------------- fallback (atomic) layout ----------------
#define FB_NDEG   (N_NODES)
#define FB_NACC   (N_NODES * D)
#define FB_FLAGS  (FB_NDEG + FB_NACC)

// ---------------------------------------------------------------------------
// dtype helpers
// ---------------------------------------------------------------------------
__device__ __forceinline__ float bf_bits(ushort_t us) {
    return __uint_as_float(((unsigned)us) << 16);
}
__device__ __forceinline__ float lo_bf(unsigned u) { return __uint_as_float(u << 16); }
__device__ __forceinline__ float hi_bf(unsigned u) { return __uint_as_float(u & 0xffff0000u); }
__device__ __forceinline__ ushort_t f2bf(float v) {
    unsigned u = __float_as_uint(v);
    unsigned r = (u + 0x7fffu + ((u >> 16) & 1u)) >> 16;
    return (ushort_t)r;
}
__device__ __forceinline__ float ld_f(const void* p, int idx, int f32) {
    return f32 ? ((const float*)p)[idx]
               : bf_bits(((const ushort_t*)p)[idx]);
}

__device__ __forceinline__ void load16(const void* __restrict__ p, long long base,
                                       int f32, float* o) {
    if (f32) {
        const float4* q = (const float4*)((const float*)p + base);
        float4 a = q[0], b = q[1], c = q[2], d = q[3];
        o[0]=a.x; o[1]=a.y; o[2]=a.z; o[3]=a.w;
        o[4]=b.x; o[5]=b.y; o[6]=b.z; o[7]=b.w;
        o[8]=c.x; o[9]=c.y; o[10]=c.z; o[11]=c.w;
        o[12]=d.x; o[13]=d.y; o[14]=d.z; o[15]=d.w;
    } else {
        const uint4* q = (const uint4*)((const ushort_t*)p + base);
        uint4 a = q[0], b = q[1];
        unsigned u[8] = {a.x, a.y, a.z, a.w, b.x, b.y, b.z, b.w};
#pragma unroll
        for (int k = 0; k < 8; k++) {
            o[2 * k]     = lo_bf(u[k]);
            o[2 * k + 1] = hi_bf(u[k]);
        }
    }
}

__device__ __forceinline__ void load_edge(const void* __restrict__ ei, int e, int is64,
                                          int& s, int& d) {
    if (is64) {
        const long long* p = (const long long*)ei;
        s = (int)p[e];
        d = (int)p[N_EDGES + e];
    } else {
        const int* p = (const int*)ei;
        s = p[e];
        d = p[N_EDGES + e];
    }
}

// Parallel flag detection (wave 0, ballot), per-block, no cross-block dep.
__device__ __forceinline__ void detect_flags_par(const void* x, const void* ei,
                                                 int* flags) {
    int t = threadIdx.x;
    if (t < 64) {
        const ushort_t* h = (const ushort_t*)x;
        int bad = 0;
#pragma unroll
        for (int k = 0; k < 4; k++) {
            float v = bf_bits(h[4 * t + k]);
            if (!(v == v) || fabsf(v) > 1.0e6f) bad = 1;
        }
        unsigned long long mb = __ballot(bad);
        const long long* p = (const long long*)ei;
        int bad64 = 0;
        if (t < 16) {
            long long v = p[t];
            bad64 = (v < 0 || v >= N_NODES) ? 1 : 0;
        }
        unsigned long long m64 = __ballot(bad64);
        if (t == 0) {
            flags[0] = mb ? 1 : 0;
            flags[1] = m64 ? 0 : 1;
        }
    }
}

__device__ __forceinline__ void stage_weights(
    const void* W1, const void* b1, const void* W2, const void* b2, int f32,
    float* sW1, float* sW2t, float* sb1, float* sb2)
{
    int t = threadIdx.x;
    for (int idx = t; idx < HID * 2 * D; idx += blockDim.x)
        sW1[idx] = ld_f(W1, idx, f32);
    for (int idx = t; idx < HID * D; idx += blockDim.x) {
        int j = idx / D, i = idx % D;
        sW2t[idx] = ld_f(W2, i * HID + j, f32);
    }
    if (t < HID) sb1[t] = ld_f(b1, t, f32);
    if (t < D)  sb2[t] = ld_f(b2, t, f32);
}

// ---------------------------------------------------------------------------
// Full-MLP per-edge math, f32 (safety + fallback paths) — proven op order.
// ---------------------------------------------------------------------------
__device__ __forceinline__ void edge_math_v4(
    const float* __restrict__ sW1, const float* __restrict__ sW2t,
    const float* __restrict__ sb1, const float* __restrict__ sb2,
    const float* xs, const float* xd, float coef,
    float* ms, float* md)
{
    float vs[D], vd[D];
#pragma unroll
    for (int i = 0; i < D; i++) { vs[i] = sb2[i]; vd[i] = sb2[i]; }
#pragma unroll 4
    for (int j = 0; j < HID; j++) {
        float hs = sb1[j], hd = sb1[j];
        const float4* w4 = (const float4*)&sW1[j * 2 * D];
#pragma unroll
        for (int t = 0; t < 4; t++) {
            float4 wv = w4[t];
            int k = 4 * t;
            hs = fmaf(wv.x, xs[k],     hs); hd = fmaf(wv.x, xd[k],     hd);
            hs = fmaf(wv.y, xs[k + 1], hs); hd = fmaf(wv.y, xd[k + 1], hd);
            hs = fmaf(wv.z, xs[k + 2], hs); hd = fmaf(wv.z, xd[k + 2], hd);
            hs = fmaf(wv.w, xs[k + 3], hs); hd = fmaf(wv.w, xd[k + 3], hd);
        }
#pragma unroll
        for (int t = 0; t < 4; t++) {
            float4 wv = w4[4 + t];
            int k = 4 * t;
            hs = fmaf(wv.x, xd[k],     hs); hd = fmaf(wv.x, xs[k],     hd);
            hs = fmaf(wv.y, xd[k + 1], hs); hd = fmaf(wv.y, xs[k + 1], hd);
            hs = fmaf(wv.z, xd[k + 2], hs); hd = fmaf(wv.z, xs[k + 2], hd);
            hs = fmaf(wv.w, xd[k + 3], hs); hd = fmaf(wv.w, xs[k + 3], hd);
        }
        hs = fmaxf(hs, 0.0f);
        hd = fmaxf(hd, 0.0f);
        const float4* w24 = (const float4*)&sW2t[j * D];
#pragma unroll
        for (int t = 0; t < 4; t++) {
            float4 u = w24[t];
            int i = 4 * t;
            vs[i]     = fmaf(u.x, hs, vs[i]);     vd[i]     = fmaf(u.x, hd, vd[i]);
            vs[i + 1] = fmaf(u.y, hs, vs[i + 1]); vd[i + 1] = fmaf(u.y, hd, vd[i + 1]);
            vs[i + 2] = fmaf(u.z, hs, vs[i + 2]); vd[i + 2] = fmaf(u.z, hd, vd[i + 2]);
            vs[i + 3] = fmaf(u.w, hs, vs[i + 3]); vd[i + 3] = fmaf(u.w, hd, vd[i + 3]);
        }
    }
    float ns = 0.0f, nd = 0.0f;
#pragma unroll
    for (int i = 0; i < D; i++) { ns = fmaf(vs[i], vs[i], ns); nd = fmaf(vd[i], vd[i], nd); }
    float is_ = 1.0f / fmaxf(sqrtf(ns), 1e-12f);
    float id_ = 1.0f / fmaxf(sqrtf(nd), 1e-12f);
#pragma unroll
    for (int i = 0; i < D; i++) { vs[i] *= is_; vd[i] *= id_; }
    float dot1 = 0.0f;
#pragma unroll
    for (int i = 0; i < D; i++) dot1 = fmaf(vd[i], xd[i], dot1);
#pragma unroll
    for (int i = 0; i < D; i++) ms[i] = fmaf(-2.0f * dot1, vd[i], xd[i]);
    float dot2 = 0.0f;
#pragma unroll
    for (int i = 0; i < D; i++) dot2 = fmaf(vs[i], ms[i], dot2);
#pragma unroll
    for (int i = 0; i < D; i++) ms[i] = coef * fmaf(-2.0f * dot2, vs[i], ms[i]);
    float dot3 = 0.0f;
#pragma unroll
    for (int i = 0; i < D; i++) dot3 = fmaf(vs[i], xs[i], dot3);
#pragma unroll
    for (int i = 0; i < D; i++) md[i] = fmaf(-2.0f * dot3, vs[i], xs[i]);
    float dot4 = 0.0f;
#pragma unroll
    for (int i = 0; i < D; i++) dot4 = fmaf(vd[i], md[i], dot4);
#pragma unroll
    for (int i = 0; i < D; i++) md[i] = coef * fmaf(-2.0f * dot4, vd[i], md[i]);
}

// ---------------------------------------------------------------------------
// bf16-path per-edge math on the SGPR-resident prep table (R3-proven, 92us).
// ---------------------------------------------------------------------------
__device__ __forceinline__ void edge_math_prep(
    const float* __restrict__ prep,
    const float* xs, const float* xd, float coef,
    float* ms, float* md)
{
    const float* b2f = prep + 64 * 64;
    float vs[D], vd[D];
#pragma unroll
    for (int i = 0; i < D; i++) { vs[i] = b2f[i]; vd[i] = b2f[i]; }

#pragma unroll 1
    for (int j = 0; j < HID; j++) {
        const float* w = prep + (j << 6);    // uniform -> s_load
        float b1j = w[48];
        float hs0 = b1j, hs1 = 0.0f, hd0 = b1j, hd1 = 0.0f;
#pragma unroll
        for (int k = 0; k < 8; k++) {        // [xs | .] part
            hs0 = fmaf(w[k],     xs[k],     hs0);
            hd0 = fmaf(w[k],     xd[k],     hd0);
            hs1 = fmaf(w[8 + k], xs[8 + k], hs1);
            hd1 = fmaf(w[8 + k], xd[8 + k], hd1);
        }
#pragma unroll
        for (int k = 0; k < 8; k++) {        // [. | xd] part
            hs0 = fmaf(w[16 + k], xd[k],     hs0);
            hd0 = fmaf(w[16 + k], xs[k],     hd0);
            hs1 = fmaf(w[24 + k], xd[8 + k], hs1);
            hd1 = fmaf(w[24 + k], xs[8 + k], hd1);
        }
        float hs = fmaxf(hs0 + hs1, 0.0f);
        float hd = fmaxf(hd0 + hd1, 0.0f);
#pragma unroll
        for (int i = 0; i < D; i++) {
            vs[i] = fmaf(w[32 + i], hs, vs[i]);
            vd[i] = fmaf(w[32 + i], hd, vd[i]);
        }
    }

    float ns = 0.0f, nd = 0.0f;
#pragma unroll
    for (int i = 0; i < D; i++) { ns = fmaf(vs[i], vs[i], ns); nd = fmaf(vd[i], vd[i], nd); }
    float is_ = 1.0f / fmaxf(sqrtf(ns), 1e-12f);
    float id_ = 1.0f / fmaxf(sqrtf(nd), 1e-12f);
#pragma unroll
    for (int i = 0; i < D; i++) { vs[i] *= is_; vd[i] *= id_; }

    float dot1 = 0.0f;
#pragma unroll
    for (int i = 0; i < D; i++) dot1 = fmaf(vd[i], xd[i], dot1);
#pragma unroll
    for (int i = 0; i < D; i++) ms[i] = fmaf(-2.0f * dot1, vd[i], xd[i]);
    float dot2 = 0.0f;
#pragma unroll
    for (int i = 0; i < D; i++) dot2 = fmaf(vs[i], ms[i], dot2);
#pragma unroll
    for (int i = 0; i < D; i++) ms[i] = coef * fmaf(-2.0f * dot2, vs[i], ms[i]);
    float dot3 = 0.0f;
#pragma unroll
    for (int i = 0; i < D; i++) dot3 = fmaf(vs[i], xs[i], dot3);
#pragma unroll
    for (int i = 0; i < D; i++) md[i] = fmaf(-2.0f * dot3, vs[i], xs[i]);
    float dot4 = 0.0f;
#pragma unroll
    for (int i = 0; i < D; i++) dot4 = fmaf(vd[i], md[i], dot4);
#pragma unroll
    for (int i = 0; i < D; i++) md[i] = coef * fmaf(-2.0f * dot4, vd[i], md[i]);
}

// Edge tail: claim slots + write both msgs (64B-aligned rows).
__device__ __forceinline__ void write_msgs(int* __restrict__ wsI, float* __restrict__ msg,
                                           int s, int d, const float* ms, const float* md)
{
    int slot_s = atomicAdd(&wsI[CUR_OFF + s], 1);
    float4* m0 = (float4*)(msg + (long long)slot_s * D);
    m0[0] = make_float4(ms[0], ms[1], ms[2], ms[3]);
    m0[1] = make_float4(ms[4], ms[5], ms[6], ms[7]);
    m0[2] = make_float4(ms[8], ms[9], ms[10], ms[11]);
    m0[3] = make_float4(ms[12], ms[13], ms[14], ms[15]);
    int slot_d = atomicAdd(&wsI[CUR_OFF + d], 1);
    float4* m1 = (float4*)(msg + (long long)slot_d * D);
    m1[0] = make_float4(md[0], md[1], md[2], md[3]);
    m1[1] = make_float4(md[4], md[5], md[6], md[7]);
    m1[2] = make_float4(md[8], md[9], md[10], md[11]);
    m1[3] = make_float4(md[12], md[13], md[14], md[15]);
}

// Weight-table packing (block-0 duty). bf16 interpretation; f32 path ignores it.
__device__ __forceinline__ void pack_prep(const void* W1, const void* b1,
                                          const void* W2, const void* b2,
                                          int* __restrict__ wsI)
{
    float* pf = (float*)(wsI + PREP_OFF);
    const ushort_t* W1b = (const ushort_t*)W1;
    const ushort_t* W2b = (const ushort_t*)W2;
    const ushort_t* b1b = (const ushort_t*)b1;
    const ushort_t* b2b = (const ushort_t*)b2;
    for (int idx = threadIdx.x; idx < 64 * 64; idx += 256) {
        int j = idx >> 6, w = idx & 63;
        float val = 0.0f;
        if (w < 32)      val = bf_bits(W1b[j * 32 + w]);
        else if (w < 48) val = bf_bits(W2b[(w - 32) * HID + j]);
        else if (w == 48) val = bf_bits(b1b[j]);
        pf[idx] = val;
    }
    if (threadIdx.x < D)
        pf[64 * 64 + threadIdx.x] = bf_bits(b2b[threadIdx.x]);
}

// Gather body for one (node, quad) pair.
__device__ __forceinline__ void gather_node(int n, int c, int f32,
                                            const int* __restrict__ wsI,
                                            const void* __restrict__ x,
                                            void* __restrict__ out)
{
    const int* off = wsI + OFF_OFF;
    const float4* msg4 = (const float4*)(wsI + MSG_OFF_I);

    int beg = off[n], end = off[n + 1];
    float4 a = make_float4(0.0f, 0.0f, 0.0f, 0.0f);
    int it = beg;
    for (; it + 2 <= end; it += 2) {
        float4 u = msg4[(long long)it * 4 + c];
        float4 v = msg4[(long long)(it + 1) * 4 + c];
        a.x += u.x + v.x; a.y += u.y + v.y; a.z += u.z + v.z; a.w += u.w + v.w;
    }
    if (it < end) {
        float4 u = msg4[(long long)it * 4 + c];
        a.x += u.x; a.y += u.y; a.z += u.z; a.w += u.w;
    }

    long long xb = (long long)n * D + 4 * c;
    float4 xv;
    if (f32) {
        xv = *(const float4*)((const float*)x + xb);
    } else {
        uint2 u = *(const uint2*)((const ushort_t*)x + xb);
        xv.x = lo_bf(u.x); xv.y = hi_bf(u.x);
        xv.z = lo_bf(u.y); xv.w = hi_bf(u.y);
    }
    float4 r;
    r.x = fmaxf(xv.x + a.x, 0.0f);
    r.y = fmaxf(xv.y + a.y, 0.0f);
    r.z = fmaxf(xv.z + a.z, 0.0f);
    r.w = fmaxf(xv.w + a.w, 0.0f);
    if (f32) {
        *(float4*)((float*)out + xb) = r;
    } else {
        uint2 o;
        o.x = (unsigned)f2bf(r.x) | ((unsigned)f2bf(r.y) << 16);
        o.y = (unsigned)f2bf(r.z) | ((unsigned)f2bf(r.w) << 16);
        *(uint2*)((ushort_t*)out + xb) = o;
    }
}

// ===========================================================================
// FUSED cooperative kernel: zero -> count -> deg/bsum -> scan -> offsets ->
// edge -> gather, with grid.sync() between phases. Eliminates 5 launch gaps
// (~10-15us each, measured across R3/R5) and the memset dispatch.
// ===========================================================================
__global__ __launch_bounds__(256) void fused_kernel(
    const void* __restrict__ x,
    const void* __restrict__ ei,
    const void* __restrict__ W1,
    const void* __restrict__ b1,
    const void* __restrict__ W2,
    const void* __restrict__ b2,
    int* __restrict__ wsI,
    void* __restrict__ out)
{
    cg::grid_group grid = cg::this_grid();

    __shared__ __align__(16) float sW1f[HID * 2 * D];   // f32 path only
    __shared__ __align__(16) float sW2tf[HID * D];      // f32 path only
    __shared__ float sb1[HID];
    __shared__ float sb2[D];
    __shared__ int sm[SCAN_B];
    __shared__ int sB[SCAN_B];
    __shared__ int sfl[2];

    detect_flags_par(x, ei, sfl);
    __syncthreads();
    const int f32 = sfl[0], i64 = sfl[1];
    const int t = threadIdx.x;
    const int gid = blockIdx.x * 256 + t;
    const int nthr = gridDim.x * 256;

    if (f32)
        stage_weights(W1, b1, W2, b2, 1, sW1f, sW2tf, sb1, sb2);
    // (block-level visibility of sW1f guaranteed by the grid.sync()s below)

    // ---- P0: zero counts; block 0 packs the weight table ----
    for (int i = gid; i < 4 * N_NODES; i += nthr) wsI[CNT4_OFF + i] = 0;
    if (blockIdx.x == 0) pack_prep(W1, b1, W2, b2, wsI);
    grid.sync();

    // ---- P1: degree counting (replicated to 4 banks to cut contention) ----
    for (int e = gid; e < N_EDGES; e += nthr) {
        int s, d;
        load_edge(ei, e, i64, s, d);
        int r = (e & 3) * N_NODES;
        atomicAdd(&wsI[CNT4_OFF + r + s], 1);
        atomicAdd(&wsI[CNT4_OFF + r + d], 1);
    }
    grid.sync();

    // ---- P2: deg = sum of replicas; per-block sum -> BS ----
    if (blockIdx.x < SCAN_G) {
        int g = blockIdx.x * SCAN_B + t;
        int c = 0;
        if (g < N_NODES) {
            c = wsI[CNT4_OFF + g] + wsI[CNT4_OFF + N_NODES + g]
              + wsI[CNT4_OFF + 2 * N_NODES + g] + wsI[CNT4_OFF + 3 * N_NODES + g];
            wsI[DEG_OFF + g] = c;
        }
        sm[t] = c;
        __syncthreads();
        for (int st = SCAN_B / 2; st > 0; st >>= 1) {
            if (t < st) sm[t] += sm[t + st];
            __syncthreads();
        }
        if (t == 0) wsI[BS_OFF + blockIdx.x] = sm[0];
    }
    grid.sync();

    // ---- P3: block 0 turns BS into exclusive block bases ----
    if (blockIdx.x == 0) {
        int v = (t < SCAN_G) ? wsI[BS_OFF + t] : 0;
        sB[t] = v;
        __syncthreads();
        for (int st = 1; st < SCAN_B; st <<= 1) {
            int u = (t >= st) ? sB[t - st] : 0;
            __syncthreads();
            sB[t] += u;
            __syncthreads();
        }
        if (t < SCAN_G) wsI[BS_OFF + t] = sB[t] - v;   // exclusive base
    }
    grid.sync();

    // ---- P4: per-block scan of deg -> OFF/CUR ----
    if (blockIdx.x < SCAN_G) {
        int base = wsI[BS_OFF + blockIdx.x];
        int g = blockIdx.x * SCAN_B + t;
        int c = (g < N_NODES) ? wsI[DEG_OFF + g] : 0;
        sm[t] = c;
        __syncthreads();
        for (int st = 1; st < SCAN_B; st <<= 1) {
            int u = (t >= st) ? sm[t - st] : 0;
            __syncthreads();
            sm[t] += u;
            __syncthreads();
        }
        int excl = sm[t] - c + base;
        if (g < N_NODES) {
            wsI[OFF_OFF + g] = excl;
            wsI[CUR_OFF + g] = excl;
            if (g == N_NODES - 1) wsI[OFF_OFF + N_NODES] = excl + c;
        }
    }
    grid.sync();

    // ---- P5: edge phase (R3-proven math, SGPR weight table) ----
    {
        const float* prep = (const float*)(wsI + PREP_OFF);
        float* msg = (float*)(wsI + MSG_OFF_I);
        for (int e = gid; e < N_EDGES; e += nthr) {
            int s, d;
            load_edge(ei, e, i64, s, d);
            float degs = (float)wsI[DEG_OFF + s];
            float degd = (float)wsI[DEG_OFF + d];
            float coef = (1.0f / sqrtf(fmaxf(degs, 1e-5f)))
                       * (1.0f / sqrtf(fmaxf(degd, 1e-5f)));
            float xs[D], xd[D];
            load16(x, (long long)s * D, f32, xs);
            load16(x, (long long)d * D, f32, xd);
            float ms[D], md[D];
            if (!f32) edge_math_prep(prep, xs, xd, coef, ms, md);
            else      edge_math_v4(sW1f, sW2tf, sb1, sb2, xs, xd, coef, ms, md);
            write_msgs(wsI, msg, s, d, ms, md);
        }
    }
    grid.sync();

    // ---- P6: gather ----
    {
        int n = gid >> 2, c = gid & 3;
        if (n < N_NODES) gather_node(n, c, f32, wsI, x, out);
    }
}

// ===========================================================================
// Fallback pipeline (R3-proven, non-cooperative)
// ===========================================================================
__global__ void csr_count_kernel(const void* __restrict__ ei,
                                 const void* __restrict__ x,
                                 const void* __restrict__ W1,
                                 const void* __restrict__ b1,
                                 const void* __restrict__ W2,
                                 const void* __restrict__ b2,
                                 int* __restrict__ wsI) {
    __shared__ int sfl[2];
    detect_flags_par(x, ei, sfl);
    __syncthreads();
    int i64 = sfl[1];

    if (blockIdx.x == 0) pack_prep(W1, b1, W2, b2, wsI);

    int e = blockIdx.x * blockDim.x + threadIdx.x;
    if (e >= N_EDGES) return;
    int s, d;
    load_edge(ei, e, i64, s, d);
    int r = (e & 3) * N_NODES;
    atomicAdd(&wsI[CNT4_OFF + r + s], 1);
    atomicAdd(&wsI[CNT4_OFF + r + d], 1);
}

__global__ __launch_bounds__(SCAN_B) void csr_scan1_kernel(int* __restrict__ wsI) {
    __shared__ int sm[SCAN_B];
    int t = threadIdx.x;
    int g = blockIdx.x * SCAN_B + t;
    int c = 0;
    if (g < N_NODES) {
        c = wsI[CNT4_OFF + g] + wsI[CNT4_OFF + N_NODES + g]
          + wsI[CNT4_OFF + 2 * N_NODES + g] + wsI[CNT4_OFF + 3 * N_NODES + g];
        wsI[DEG_OFF + g] = c;
    }
    sm[t] = c;
    __syncthreads();
    for (int st = SCAN_B / 2; st > 0; st >>= 1) {
        if (t < st) sm[t] += sm[t + st];
        __syncthreads();
    }
    if (t == 0) wsI[BS_OFF + blockIdx.x] = sm[0];
}

__global__ __launch_bounds__(SCAN_B) void csr_scan3_kernel(int* __restrict__ wsI) {
    __shared__ int sB[SCAN_B];
    __shared__ int sm[SCAN_B];
    int t = threadIdx.x;
    int bsv = (t < SCAN_G) ? wsI[BS_OFF + t] : 0;
    sB[t] = bsv;
    __syncthreads();
    for (int st = 1; st < SCAN_B; st <<= 1) {
        int u = (t >= st) ? sB[t - st] : 0;
        __syncthreads();
        sB[t] += u;
        __syncthreads();
    }
    int blockBase = sB[blockIdx.x] - wsI[BS_OFF + blockIdx.x];

    int g = blockIdx.x * SCAN_B + t;
    int c = (g < N_NODES) ? wsI[DEG_OFF + g] : 0;
    sm[t] = c;
    __syncthreads();
    for (int st = 1; st < SCAN_B; st <<= 1) {
        int u = (t >= st) ? sm[t - st] : 0;
        __syncthreads();
        sm[t] += u;
        __syncthreads();
    }
    int excl = sm[t] - c + blockBase;
    if (g < N_NODES) {
        wsI[OFF_OFF + g] = excl;
        wsI[CUR_OFF + g] = excl;
        if (g == N_NODES - 1) wsI[OFF_OFF + N_NODES] = excl + c;
    }
}

__global__ __launch_bounds__(256) void csr_edge_kernel(
    const void* __restrict__ x,
    const void* __restrict__ ei,
    const void* __restrict__ W1,
    const void* __restrict__ b1,
    const void* __restrict__ W2,
    const void* __restrict__ b2,
    const float* __restrict__ prep,
    int* __restrict__ wsI)
{
    __shared__ __align__(16) float sW1f[HID * 2 * D];
    __shared__ __align__(16) float sW2tf[HID * D];
    __shared__ float sb1[HID];
    __shared__ float sb2[D];
    __shared__ int sfl[2];

    detect_flags_par(x, ei, sfl);
    __syncthreads();
    int f32 = sfl[0], i64 = sfl[1];
    int t = threadIdx.x;

    if (f32) {
        stage_weights(W1, b1, W2, b2, 1, sW1f, sW2tf, sb1, sb2);
        __syncthreads();
    }

    int e = blockIdx.x * 256 + t;
    if (e >= N_EDGES) return;

    int s, d;
    load_edge(ei, e, i64, s, d);
    float degs = (float)wsI[DEG_OFF + s];
    float degd = (float)wsI[DEG_OFF + d];
    float coef = (1.0f / sqrtf(fmaxf(degs, 1e-5f))) * (1.0f / sqrtf(fmaxf(degd, 1e-5f)));
    float* msg = (float*)(wsI + MSG_OFF_I);

    float xs[D], xd[D];
    load16(x, (long long)s * D, f32, xs);
    load16(x, (long long)d * D, f32, xd);

    float ms[D], md[D];
    if (!f32) edge_math_prep(prep, xs, xd, coef, ms, md);
    else      edge_math_v4(sW1f, sW2tf, sb1, sb2, xs, xd, coef, ms, md);
    write_msgs(wsI, msg, s, d, ms, md);
}

__global__ __launch_bounds__(256) void csr_gather_kernel(
    const void* __restrict__ x,
    const void* __restrict__ ei,
    const int* __restrict__ wsI,
    void* __restrict__ out)
{
    __shared__ int sfl[2];
    detect_flags_par(x, ei, sfl);
    __syncthreads();
    int f32 = sfl[0];

    int n = blockIdx.x * 64 + (threadIdx.x >> 2);
    int c = threadIdx.x & 3;
    if (n >= N_NODES) return;
    gather_node(n, c, f32, wsI, x, out);
}

// ===========================================================================
// Fallback path (tiny workspace): float atomics into acc (known-good)
// ===========================================================================
__global__ void fb_init_kernel(float* __restrict__ ws,
                               const void* __restrict__ x,
                               const void* __restrict__ ei) {
    int i = blockIdx.x * blockDim.x + threadIdx.x;
    if (i < FB_FLAGS) ws[i] = 0.0f;
    if (blockIdx.x == 0)
        detect_flags_par(x, ei, (int*)(ws + FB_FLAGS));
}

__global__ void fb_deg_kernel(const void* __restrict__ ei, float* __restrict__ ws) {
    int i64 = ((const int*)(ws + FB_FLAGS))[1];
    int e = blockIdx.x * blockDim.x + threadIdx.x;
    if (e >= N_EDGES) return;
    int s, d;
    load_edge(ei, e, i64, s, d);
    atomicAdd(&ws[s], 1.0f);
    atomicAdd(&ws[d], 1.0f);
}

__global__ __launch_bounds__(256) void fb_edge_kernel(
    const void* __restrict__ x, const void* __restrict__ ei,
    const void* __restrict__ W1, const void* __restrict__ b1,
    const void* __restrict__ W2, const void* __restrict__ b2,
    float* __restrict__ ws)
{
    __shared__ __align__(16) float sW1[HID * 2 * D];
    __shared__ __align__(16) float sW2t[HID * D];
    __shared__ float sb1[HID];
    __shared__ float sb2[D];
    const int* flags = (const int*)(ws + FB_FLAGS);
    int f32 = flags[0], i64 = flags[1];
    stage_weights(W1, b1, W2, b2, f32, sW1, sW2t, sb1, sb2);
    __syncthreads();
    int e = blockIdx.x * blockDim.x + threadIdx.x;
    if (e >= N_EDGES) return;
    int s, d;
    load_edge(ei, e, i64, s, d);
    float xs[D], xd[D];
    load16(x, (long long)s * D, f32, xs);
    load16(x, (long long)d * D, f32, xd);
    float coef = (1.0f / sqrtf(fmaxf(ws[s], 1e-5f))) * (1.0f / sqrtf(fmaxf(ws[d], 1e-5f)));
    float ms[D], md[D];
    edge_math_v4(sW1, sW2t, sb1, sb2, xs, xd, coef, ms, md);
    float* acc = ws + FB_NDEG;
#pragma unroll
    for (int i = 0; i < D; i++) atomicAdd(&acc[(long long)s * D + i], ms[i]);
#pragma unroll
    for (int i = 0; i < D; i++) atomicAdd(&acc[(long long)d * D + i], md[i]);
}

__global__ void fb_finalize_kernel(const void* __restrict__ x,
                                   const float* __restrict__ ws,
                                   void* __restrict__ out)
{
    int f32 = ((const int*)(ws + FB_FLAGS))[0];
    const float* acc = ws + FB_NDEG;
    int i = blockIdx.x * blockDim.x + threadIdx.x;
    if (i >= FB_NACC) return;
    float v = ld_f(x, i, f32) + acc[i];
    v = fmaxf(v, 0.0f);
    if (f32) ((float*)out)[i] = v;
    else     ((__hip_bfloat16*)out)[i] = __float2bfloat16(v);
}

// ===========================================================================
extern "C" void kernel_launch(void* const* d_in, const int* in_sizes, int n_in,
                              void* d_out, int out_size, void* d_ws, size_t ws_size,
                              hipStream_t stream)
{
    const void* x  = d_in[0];
    const void* ei = d_in[1];
    const void* W1 = d_in[2];
    const void* b1 = d_in[3];
    const void* W2 = d_in[4];
    const void* b2 = d_in[5];

    int blk = 256;
    if (ws_size >= CSR_NEEDED_BYTES) {
        int* wsI = (int*)d_ws;

        // ---- try the fused cooperative kernel ----
        int maxBlocksPerCU = 0;
        hipError_t oe = hipOccupancyMaxActiveBlocksPerMultiprocessor(
            &maxBlocksPerCU, fused_kernel, 256, 0);
        int grid = 1024;                                   // 4 blocks/CU default
        if (oe == hipSuccess && maxBlocksPerCU > 0) {
            long long cap = (long long)maxBlocksPerCU * 256; // 256 CUs (gfx950)
            if (cap < grid) grid = (int)cap;
            else if (cap >= 2048) grid = 2048;
        }
        if (grid >= 782) {                                 // gather needs >=782 blocks
            void* wsp = (void*)wsI;
            void* kargs[] = {(void*)&x, (void*)&ei, (void*)&W1, (void*)&b1,
                             (void*)&W2, (void*)&b2, (void*)&wsp, (void*)&d_out};
            hipError_t le = hipLaunchCooperativeKernel(
                (const void*)fused_kernel, dim3(grid), dim3(256), kargs, 0, stream);
            if (le == hipSuccess) return;
            (void)hipGetLastError();                       // clear sticky error
        }

        // ---- fallback: proven R3 sequence ----
        hipMemsetAsync(d_ws, 0, (size_t)4 * N_NODES * sizeof(int), stream);
        csr_count_kernel<<<(N_EDGES + blk - 1) / blk, blk, 0, stream>>>(
            ei, x, W1, b1, W2, b2, wsI);
        csr_scan1_kernel<<<SCAN_G, SCAN_B, 0, stream>>>(wsI);
        csr_scan3_kernel<<<SCAN_G, SCAN_B, 0, stream>>>(wsI);
        csr_edge_kernel<<<(N_EDGES + blk - 1) / blk, blk, 0, stream>>>(
            x, ei, W1, b1, W2, b2, (const float*)(wsI + PREP_OFF), wsI);
        csr_gather_kernel<<<(N_NODES + 63) / 64, blk, 0, stream>>>(x, ei, wsI, d_out);
    } else {
        float* ws = (float*)d_ws;
        fb_init_kernel<<<(FB_FLAGS + blk - 1) / blk, blk, 0, stream>>>(ws, x, ei);
        fb_deg_kernel<<<(N_EDGES + blk - 1) / blk, blk, 0, stream>>>(ei, ws);
        fb_edge_kernel<<<(N_EDGES + blk - 1) / blk, blk, 0, stream>>>(x, ei, W1, b1, W2, b2, ws);
        fb_finalize_kernel<<<(FB_NACC + blk - 1) / blk, blk, 0, stream>>>(x, ws, d_out);
    }
}